// Round 4
// baseline (84.751 us; speedup 1.0000x reference)
//
#include <hip/hip_runtime.h>
#include <hip/hip_bf16.h>

// FourierResistor: B=8, N=4096, d=128, H=4, fp32 in/out.
// sum-minus-self decomposition:
//   f[k,b,n,d]  = S[k,b,d] - xe[k,b,n,d],  S = sum_n xe
//   inv[b,n,h,d]= (T[b,h,d] - rfe[b,n,h,d]) / N,  T = sum_n rfe
// Pipeline (no memset, no atomics-to-global):
//   K1 gemm: x1 = x @ W_lt^T  + per-block partial S -> PS   (MFMA bf16)
//   finS   : S0,S1 from PS                                  (tiny)
//   K3 gemm: phi = (x1+pos)@W_phi^T + b  + partial T -> PT  (bf16 phi out)
//   finT   : T from PT                                      (tiny)
//   K5     : comb MLP + m=x1+comb + LN -> mn (bf16)
//   K6     : out = relu(mn@Wf1^T+b)@Wf2^T + b (fused FFN)

#define DEV __device__ __forceinline__

typedef __attribute__((ext_vector_type(8))) short bf16x8;
typedef __attribute__((ext_vector_type(4))) float f32x4;

constexpr int Bb = 8, Nn = 4096;
constexpr int BN = Bb * Nn;     // 32768
constexpr int LDP = 136;        // padded LDS pitch in bf16 elems (272 B)

union U8 { ushort u[8]; uint4 v; };

static DEV ushort f2bf(float f) {
    __hip_bfloat16 h = __float2bfloat16(f);
    return *reinterpret_cast<ushort*>(&h);
}

// ---------------------------------------------------------------------------
// MFMA GEMM, K=128, out tile 64 rows x 128 cols, 256 thr (4 waves x 16 rows).
// MODE 0: x1 = x @ Wlt^T, partial S -> PS          (f32 in, f32 out)
// MODE 1: phi = (x1+pos)@Wphi^T + b, partial T->PT (f32 in, bf16 out, bid.y=h)
// ---------------------------------------------------------------------------
template <int MODE>
__global__ __launch_bounds__(256) void k_mfma_gemm(
    const float* __restrict__ X, const float* __restrict__ W,
    const float* __restrict__ bias, const float* __restrict__ pos,
    float* __restrict__ outF, ushort* __restrict__ outB,
    float* __restrict__ PS, float* __restrict__ PT,
    const float* __restrict__ S0c, const float* __restrict__ S1c)
{
    __shared__ __align__(16) ushort xs[64 * LDP];    // 17 KB
    __shared__ __align__(16) ushort wsl[128 * LDP];  // 34 KB
    __shared__ float red[256];                       // S or T partial combine
    const int t = threadIdx.x;
    const int row0 = blockIdx.x * 64;
    const int jt = (MODE == 1) ? blockIdx.y : 0;

    red[t] = 0.f;

    {   // stage X tile (64 rows x 128), fp32 -> bf16 (+pos for MODE 1)
        #pragma unroll
        for (int i = 0; i < 4; ++i) {
            int e = t + i * 256, r = e >> 4, c = (e & 15) * 8;
            const float* p = X + (size_t)(row0 + r) * 128 + c;
            float4 a = *reinterpret_cast<const float4*>(p);
            float4 b = *reinterpret_cast<const float4*>(p + 4);
            if (MODE == 1) {
                int n = (row0 + r) & (Nn - 1);
                const float* q = pos + (size_t)n * 128 + c;
                float4 pa = *reinterpret_cast<const float4*>(q);
                float4 pb = *reinterpret_cast<const float4*>(q + 4);
                a.x += pa.x; a.y += pa.y; a.z += pa.z; a.w += pa.w;
                b.x += pb.x; b.y += pb.y; b.z += pb.z; b.w += pb.w;
            }
            U8 u;
            u.u[0] = f2bf(a.x); u.u[1] = f2bf(a.y); u.u[2] = f2bf(a.z); u.u[3] = f2bf(a.w);
            u.u[4] = f2bf(b.x); u.u[5] = f2bf(b.y); u.u[6] = f2bf(b.z); u.u[7] = f2bf(b.w);
            *reinterpret_cast<uint4*>(xs + r * LDP + c) = u.v;
        }
    }
    {   // stage W col-tile (128 rows x 128), fp32 -> bf16
        const float* Wt = W + (size_t)jt * 128 * 128;
        #pragma unroll
        for (int i = 0; i < 8; ++i) {
            int e = t + i * 256, r = e >> 4, c = (e & 15) * 8;
            const float* p = Wt + (size_t)r * 128 + c;
            float4 a = *reinterpret_cast<const float4*>(p);
            float4 b = *reinterpret_cast<const float4*>(p + 4);
            U8 u;
            u.u[0] = f2bf(a.x); u.u[1] = f2bf(a.y); u.u[2] = f2bf(a.z); u.u[3] = f2bf(a.w);
            u.u[4] = f2bf(b.x); u.u[5] = f2bf(b.y); u.u[6] = f2bf(b.z); u.u[7] = f2bf(b.w);
            *reinterpret_cast<uint4*>(wsl + r * LDP + c) = u.v;
        }
    }
    __syncthreads();

    const int w = t >> 6, l = t & 63;
    const int lr = l & 15;
    const int lk = (l >> 4) * 8;

    f32x4 acc[8];
    #pragma unroll
    for (int cf = 0; cf < 8; ++cf) acc[cf] = f32x4{0.f, 0.f, 0.f, 0.f};

    #pragma unroll
    for (int ks = 0; ks < 4; ++ks) {
        bf16x8 a = *reinterpret_cast<const bf16x8*>(xs + (w * 16 + lr) * LDP + ks * 32 + lk);
        #pragma unroll
        for (int cf = 0; cf < 8; ++cf) {
            bf16x8 b = *reinterpret_cast<const bf16x8*>(wsl + (cf * 16 + lr) * LDP + ks * 32 + lk);
            acc[cf] = __builtin_amdgcn_mfma_f32_16x16x32_bf16(a, b, acc[cf], 0, 0, 0);
        }
    }

    // ---- epilogue: C/D layout col=lane&15, row=(lane>>4)*4+reg ----
    const int bidb = row0 >> 12;  // batch of this row-chunk
    #pragma unroll
    for (int cf = 0; cf < 8; ++cf) {
        int col = cf * 16 + lr;
        if (MODE == 0) {
            float s0c = 0.f, s1c = 0.f;
            #pragma unroll
            for (int reg = 0; reg < 4; ++reg) {
                int r = row0 + w * 16 + (l >> 4) * 4 + reg;
                float o = acc[cf][reg];
                outF[(size_t)r * 128 + col] = o;
                int n = r & (Nn - 1);
                float2 p2 = *reinterpret_cast<const float2*>(pos + (size_t)n * 128 + (col & ~1));
                s0c += o * p2.y;   // * c
                s1c += o * p2.x;   // * s
            }
            s0c += __shfl_xor(s0c, 16); s0c += __shfl_xor(s0c, 32);
            s1c += __shfl_xor(s1c, 16); s1c += __shfl_xor(s1c, 32);
            if ((l >> 4) == 0) {
                atomicAdd(&red[col], s0c);
                atomicAdd(&red[128 + col], s1c);
            }
        } else {
            float S0v = S0c[bidb * 128 + col];
            float S1v = S1c[bidb * 128 + col];
            float bv = bias[jt * 128 + col];
            float tp = 0.f;
            #pragma unroll
            for (int reg = 0; reg < 4; ++reg) {
                int r = row0 + w * 16 + (l >> 4) * 4 + reg;
                float o = acc[cf][reg] + bv;   // phi (fp32)
                outB[(size_t)r * 512 + jt * 128 + col] = f2bf(o);
                int n = r & (Nn - 1);
                float xv = X[(size_t)r * 128 + col];
                float2 p2 = *reinterpret_cast<const float2*>(pos + (size_t)n * 128 + (col & ~1));
                float cc = p2.y, ss = p2.x;
                float f0 = S0v - xv * cc;
                float f1 = xv * ss - S1v;
                float fn = sqrtf(f0 * f0 + f1 * f1);
                float fec = f0 * cc - f1 * ss;
                float res = fmaxf(0.f, fminf(1.f, fn - o));
                tp += res * fec;
            }
            tp += __shfl_xor(tp, 16); tp += __shfl_xor(tp, 32);
            if ((l >> 4) == 0) atomicAdd(&red[col], tp);
        }
    }
    __syncthreads();
    if (MODE == 0) {
        PS[(size_t)blockIdx.x * 256 + t] = red[t];
    } else if (t < 128) {
        PT[((size_t)blockIdx.x * 4 + jt) * 128 + t] = red[t];
    }
}

// ---------------------------------------------------------------------------
// finS: S0[b*128+d], S1[b*128+d] = sum over 64 chunks of PS
// ---------------------------------------------------------------------------
__global__ __launch_bounds__(256) void k_finS(
    const float* __restrict__ PS, float* __restrict__ S0, float* __restrict__ S1)
{
    int b = blockIdx.x, t = threadIdx.x;   // t = g*128 + d
    float s = 0.f;
    #pragma unroll 8
    for (int c = 0; c < 64; ++c) s += PS[(size_t)(b * 64 + c) * 256 + t];
    if (t < 128) S0[b * 128 + t] = s;
    else         S1[b * 128 + (t - 128)] = s;
}

// ---------------------------------------------------------------------------
// finT: T[idx] = sum over 64 chunks of PT;  idx = b*512 + h*128 + d
// ---------------------------------------------------------------------------
__global__ __launch_bounds__(256) void k_finT(
    const float* __restrict__ PT, float* __restrict__ T)
{
    int idx = blockIdx.x * 256 + threadIdx.x;   // 0..4095
    int b = idx >> 9, lo = idx & 511;
    float s = 0.f;
    #pragma unroll 8
    for (int c = 0; c < 64; ++c) s += PT[(size_t)b * 32768 + c * 512 + lo];
    T[idx] = s;
}

// ---------------------------------------------------------------------------
// K5: per row: inv -> comb MLP -> m = x1+comb -> LayerNorm -> mn (bf16)
// ---------------------------------------------------------------------------
__global__ __launch_bounds__(256) void k_comb_ln(
    const float* __restrict__ x1, const ushort* __restrict__ phi,
    const float* __restrict__ pos, const float* __restrict__ S0,
    const float* __restrict__ S1, const float* __restrict__ T,
    const float* __restrict__ Wc1, const float* __restrict__ bc1,
    const float* __restrict__ Wc2, const float* __restrict__ bc2,
    const float* __restrict__ lng, const float* __restrict__ lnb,
    ushort* __restrict__ mnB)
{
    int w = threadIdx.x >> 6, l = threadIdx.x & 63;
    int rrow = blockIdx.x * 4 + w;
    int b = rrow >> 12;
    int n = rrow & 4095;

    float m[2];
    #pragma unroll
    for (int q = 0; q < 2; ++q) {
        int d = l + q * 64;
        float xv = x1[(size_t)rrow * 128 + d];
        float2 p2 = *reinterpret_cast<const float2*>(pos + (size_t)n * 128 + (d & ~1));
        float cc = p2.y, ss = p2.x;
        float f0 = S0[b * 128 + d] - xv * cc;
        float f1 = xv * ss - S1[b * 128 + d];
        float fn = sqrtf(f0 * f0 + f1 * f1);
        float fec = f0 * cc - f1 * ss;
        float inv[4];
        #pragma unroll
        for (int h = 0; h < 4; ++h) {
            float ph = __bfloat162float(*reinterpret_cast<const __hip_bfloat16*>(phi + (size_t)rrow * 512 + h * 128 + d));
            float res = fmaxf(0.f, fminf(1.f, fn - ph));
            float rfe = res * fec;
            inv[h] = (T[(b * 4 + h) * 128 + d] - rfe) * (1.f / (float)Nn);
        }
        float comb = bc2[0];
        #pragma unroll
        for (int h = 0; h < 4; ++h) {
            float u = bc1[h];
            #pragma unroll
            for (int h2 = 0; h2 < 4; ++h2) u += Wc1[h * 4 + h2] * inv[h2];
            comb += fmaxf(u, 0.f) * Wc2[h];
        }
        m[q] = xv + comb;
    }

    float s = m[0] + m[1];
    #pragma unroll
    for (int off = 32; off; off >>= 1) s += __shfl_xor(s, off);
    float mu = s * (1.f / 128.f);
    float d0 = m[0] - mu, d1 = m[1] - mu;
    float v = d0 * d0 + d1 * d1;
    #pragma unroll
    for (int off = 32; off; off >>= 1) v += __shfl_xor(v, off);
    float rstd = rsqrtf(v * (1.f / 128.f) + 1e-6f);
    mnB[(size_t)rrow * 128 + l]      = f2bf(d0 * rstd * lng[l] + lnb[l]);
    mnB[(size_t)rrow * 128 + l + 64] = f2bf(d1 * rstd * lng[l + 64] + lnb[l + 64]);
}

// ---------------------------------------------------------------------------
// K6: fused FFN: out = relu(mn @ Wf1^T + b1) @ Wf2^T + b2
// ---------------------------------------------------------------------------
__global__ __launch_bounds__(256) void k_ffn(
    const ushort* __restrict__ mnB, const float* __restrict__ Wf1,
    const float* __restrict__ bf1, const float* __restrict__ Wf2,
    const float* __restrict__ bf2, float* __restrict__ out)
{
    __shared__ __align__(16) ushort xs[64 * LDP];
    __shared__ __align__(16) ushort wsl[128 * LDP];
    const int t = threadIdx.x;
    const int row0 = blockIdx.x * 64;

    #pragma unroll
    for (int i = 0; i < 4; ++i) {
        int e = t + i * 256, r = e >> 4, c = (e & 15) * 8;
        uint4 v = *reinterpret_cast<const uint4*>(mnB + (size_t)(row0 + r) * 128 + c);
        *reinterpret_cast<uint4*>(xs + r * LDP + c) = v;
    }
    #pragma unroll
    for (int i = 0; i < 8; ++i) {
        int e = t + i * 256, r = e >> 4, c = (e & 15) * 8;
        const float* p = Wf1 + (size_t)r * 128 + c;
        float4 a = *reinterpret_cast<const float4*>(p);
        float4 b = *reinterpret_cast<const float4*>(p + 4);
        U8 u;
        u.u[0] = f2bf(a.x); u.u[1] = f2bf(a.y); u.u[2] = f2bf(a.z); u.u[3] = f2bf(a.w);
        u.u[4] = f2bf(b.x); u.u[5] = f2bf(b.y); u.u[6] = f2bf(b.z); u.u[7] = f2bf(b.w);
        *reinterpret_cast<uint4*>(wsl + r * LDP + c) = u.v;
    }
    __syncthreads();

    const int w = t >> 6, l = t & 63;
    const int lr = l & 15;
    const int lk = (l >> 4) * 8;

    f32x4 acc[8];
    #pragma unroll
    for (int cf = 0; cf < 8; ++cf) acc[cf] = f32x4{0.f, 0.f, 0.f, 0.f};
    #pragma unroll
    for (int ks = 0; ks < 4; ++ks) {
        bf16x8 a = *reinterpret_cast<const bf16x8*>(xs + (w * 16 + lr) * LDP + ks * 32 + lk);
        #pragma unroll
        for (int cf = 0; cf < 8; ++cf) {
            bf16x8 b = *reinterpret_cast<const bf16x8*>(wsl + (cf * 16 + lr) * LDP + ks * 32 + lk);
            acc[cf] = __builtin_amdgcn_mfma_f32_16x16x32_bf16(a, b, acc[cf], 0, 0, 0);
        }
    }

    __syncthreads();  // all MFMA reads of xs/wsl done

    // h1 = relu(acc + b1) -> back into xs (bf16)
    #pragma unroll
    for (int cf = 0; cf < 8; ++cf) {
        int col = cf * 16 + lr;
        float bv = bf1[col];
        #pragma unroll
        for (int reg = 0; reg < 4; ++reg) {
            int rl = w * 16 + (l >> 4) * 4 + reg;
            xs[rl * LDP + col] = f2bf(fmaxf(acc[cf][reg] + bv, 0.f));
        }
    }
    // restage wsl with Wf2
    #pragma unroll
    for (int i = 0; i < 8; ++i) {
        int e = t + i * 256, r = e >> 4, c = (e & 15) * 8;
        const float* p = Wf2 + (size_t)r * 128 + c;
        float4 a = *reinterpret_cast<const float4*>(p);
        float4 b = *reinterpret_cast<const float4*>(p + 4);
        U8 u;
        u.u[0] = f2bf(a.x); u.u[1] = f2bf(a.y); u.u[2] = f2bf(a.z); u.u[3] = f2bf(a.w);
        u.u[4] = f2bf(b.x); u.u[5] = f2bf(b.y); u.u[6] = f2bf(b.z); u.u[7] = f2bf(b.w);
        *reinterpret_cast<uint4*>(wsl + r * LDP + c) = u.v;
    }
    __syncthreads();

    #pragma unroll
    for (int cf = 0; cf < 8; ++cf) acc[cf] = f32x4{0.f, 0.f, 0.f, 0.f};
    #pragma unroll
    for (int ks = 0; ks < 4; ++ks) {
        bf16x8 a = *reinterpret_cast<const bf16x8*>(xs + (w * 16 + lr) * LDP + ks * 32 + lk);
        #pragma unroll
        for (int cf = 0; cf < 8; ++cf) {
            bf16x8 b = *reinterpret_cast<const bf16x8*>(wsl + (cf * 16 + lr) * LDP + ks * 32 + lk);
            acc[cf] = __builtin_amdgcn_mfma_f32_16x16x32_bf16(a, b, acc[cf], 0, 0, 0);
        }
    }

    #pragma unroll
    for (int cf = 0; cf < 8; ++cf) {
        int col = cf * 16 + lr;
        float bv = bf2[col];
        #pragma unroll
        for (int reg = 0; reg < 4; ++reg) {
            int r = row0 + w * 16 + (l >> 4) * 4 + reg;
            out[(size_t)r * 128 + col] = acc[cf][reg] + bv;
        }
    }
}

// ---------------------------------------------------------------------------
extern "C" void kernel_launch(void* const* d_in, const int* in_sizes, int n_in,
                              void* d_out, int out_size, void* d_ws, size_t ws_size,
                              hipStream_t stream)
{
    const float* x    = (const float*)d_in[0];
    const float* pos  = (const float*)d_in[1];
    const float* Wlt  = (const float*)d_in[2];
    const float* Wphi = (const float*)d_in[3];
    const float* bphi = (const float*)d_in[4];
    const float* Wc1  = (const float*)d_in[5];
    const float* bc1  = (const float*)d_in[6];
    const float* Wc2  = (const float*)d_in[7];
    const float* bc2  = (const float*)d_in[8];
    const float* lng  = (const float*)d_in[9];
    const float* lnb  = (const float*)d_in[10];
    const float* Wf1  = (const float*)d_in[11];
    const float* bf1  = (const float*)d_in[12];
    const float* Wf2  = (const float*)d_in[13];
    const float* bf2  = (const float*)d_in[14];

    float* ws = (float*)d_ws;
    float* x1   = ws;                          // [BN*128] f32          (16 MB)
    ushort* mnB = (ushort*)(ws + 4194304);     // [BN*128] bf16         ( 8 MB)
    float* S0   = ws + 6291456;                // [1024]
    float* S1   = S0 + 1024;                   // [1024]
    float* T    = S1 + 1024;                   // [4096]
    float* PS   = T + 4096;                    // [512*256]             (512 KB)
    float* PT   = PS + 131072;                 // [512*4*128]           ( 1 MB)
    ushort* phi = (ushort*)(PT + 262144);      // [BN*512] bf16         (32 MB)
    float* out  = (float*)d_out;

    k_mfma_gemm<0><<<dim3(BN / 64), 256, 0, stream>>>(
        x, Wlt, nullptr, pos, x1, nullptr, PS, nullptr, nullptr, nullptr);
    k_finS<<<dim3(Bb), 256, 0, stream>>>(PS, S0, S1);
    k_mfma_gemm<1><<<dim3(BN / 64, 4), 256, 0, stream>>>(
        x1, Wphi, bphi, pos, nullptr, phi, nullptr, PT, S0, S1);
    k_finT<<<dim3(16), 256, 0, stream>>>(PT, T);
    k_comb_ln<<<dim3(BN / 4), 256, 0, stream>>>(x1, phi, pos, S0, S1, T,
                                                Wc1, bc1, Wc2, bc2, lng, lnb, mnB);
    k_ffn<<<dim3(BN / 64), 256, 0, stream>>>(mnB, Wf1, bf1, Wf2, bf2, out);
}

// Round 5
// 71.436 us; speedup vs baseline: 1.1864x; 1.1864x over previous
//
#include <hip/hip_runtime.h>
#include <hip/hip_bf16.h>

// FourierResistor: B=8, N=4096, d=128, H=4, fp32 in/out.
// sum-minus-self decomposition:
//   f[k,b,n,d]  = S[k,b,d] - xe[k,b,n,d],  S = sum_n xe
//   inv[b,n,h,d]= (T[b,h,d] - rfe[b,n,h,d]) / N,  T = sum_n rfe
// Pipeline (no memset, no global atomics, light GEMM epilogues):
//   K1 gemm: x1b = bf16(x @ W_lt^T)              (MFMA, LDS-restaged stores)
//   K2     : PS partials of S0,S1 from x1b       (512 blocks, vectorized)
//   finS   : S0,S1
//   K3 gemm: phi = bf16((x1+pos)@W_phi^T + b)    (4 col tiles, restaged stores)
//   K4     : PT partials of T from x1b,phi,S     (512 blocks, vectorized)
//   finT   : T
//   K5     : comb MLP + m + LayerNorm -> mnB     (wave per row)
//   K6     : out = relu(mn@Wf1^T+b1)@Wf2^T + b2  (fused FFN)

#define DEV __device__ __forceinline__

typedef __attribute__((ext_vector_type(8))) short bf16x8;
typedef __attribute__((ext_vector_type(4))) float f32x4;

constexpr int Bb = 8, Nn = 4096;
constexpr int BN = Bb * Nn;     // 32768
constexpr int LDP = 136;        // padded LDS pitch in bf16 elems (272 B)

union U8 { ushort u[8]; uint4 v; };

static DEV ushort f2bf(float f) {
    __hip_bfloat16 h = __float2bfloat16(f);
    return *reinterpret_cast<unsigned short*>(&h);
}
static DEV float bf2f(ushort u) {
    return __bfloat162float(*reinterpret_cast<const __hip_bfloat16*>(&u));
}

// ---------------------------------------------------------------------------
// MFMA GEMM, K=128, tile 64 rows x 128 cols, 256 thr (4 waves x 16 rows).
// MODE 0: x1b = bf16(x @ Wlt^T)            (f32 in, bf16 out, no bias)
// MODE 1: phi = bf16((x1+pos)@Wphi^T + b)  (bf16 in, bf16 out, bid.y col tile)
// Stores go through xs (LDS) for 16B-coalesced global writes.
// ---------------------------------------------------------------------------
template <int MODE>
__global__ __launch_bounds__(256) void k_mfma_gemm(
    const void* __restrict__ Xv, const float* __restrict__ W,
    const float* __restrict__ bias, const float* __restrict__ pos,
    ushort* __restrict__ outB)
{
    __shared__ __align__(16) ushort xs[64 * LDP];    // 17 KB
    __shared__ __align__(16) ushort wsl[128 * LDP];  // 34 KB
    const int t = threadIdx.x;
    const int row0 = blockIdx.x * 64;
    const int jt = (MODE == 1) ? blockIdx.y : 0;

    // ---- stage X tile (64 rows x 128) as bf16 ----
    if (MODE == 0) {
        const float* X = (const float*)Xv;
        #pragma unroll
        for (int i = 0; i < 4; ++i) {
            int e = t + i * 256, r = e >> 4, c = (e & 15) * 8;
            const float* p = X + (size_t)(row0 + r) * 128 + c;
            float4 a = *reinterpret_cast<const float4*>(p);
            float4 b = *reinterpret_cast<const float4*>(p + 4);
            U8 u;
            u.u[0] = f2bf(a.x); u.u[1] = f2bf(a.y); u.u[2] = f2bf(a.z); u.u[3] = f2bf(a.w);
            u.u[4] = f2bf(b.x); u.u[5] = f2bf(b.y); u.u[6] = f2bf(b.z); u.u[7] = f2bf(b.w);
            *reinterpret_cast<uint4*>(xs + r * LDP + c) = u.v;
        }
    } else {
        const ushort* X = (const ushort*)Xv;   // x1b
        #pragma unroll
        for (int i = 0; i < 4; ++i) {
            int e = t + i * 256, r = e >> 4, c = (e & 15) * 8;
            U8 u;
            u.v = *reinterpret_cast<const uint4*>(X + (size_t)(row0 + r) * 128 + c);
            int n = (row0 + r) & (Nn - 1);
            const float* q = pos + (size_t)n * 128 + c;
            float4 pa = *reinterpret_cast<const float4*>(q);
            float4 pb = *reinterpret_cast<const float4*>(q + 4);
            u.u[0] = f2bf(bf2f(u.u[0]) + pa.x);
            u.u[1] = f2bf(bf2f(u.u[1]) + pa.y);
            u.u[2] = f2bf(bf2f(u.u[2]) + pa.z);
            u.u[3] = f2bf(bf2f(u.u[3]) + pa.w);
            u.u[4] = f2bf(bf2f(u.u[4]) + pb.x);
            u.u[5] = f2bf(bf2f(u.u[5]) + pb.y);
            u.u[6] = f2bf(bf2f(u.u[6]) + pb.z);
            u.u[7] = f2bf(bf2f(u.u[7]) + pb.w);
            *reinterpret_cast<uint4*>(xs + r * LDP + c) = u.v;
        }
    }
    // ---- stage W col-tile (128 rows x 128) as bf16 ----
    {
        const float* Wt = W + (size_t)jt * 128 * 128;
        #pragma unroll
        for (int i = 0; i < 8; ++i) {
            int e = t + i * 256, r = e >> 4, c = (e & 15) * 8;
            const float* p = Wt + (size_t)r * 128 + c;
            float4 a = *reinterpret_cast<const float4*>(p);
            float4 b = *reinterpret_cast<const float4*>(p + 4);
            U8 u;
            u.u[0] = f2bf(a.x); u.u[1] = f2bf(a.y); u.u[2] = f2bf(a.z); u.u[3] = f2bf(a.w);
            u.u[4] = f2bf(b.x); u.u[5] = f2bf(b.y); u.u[6] = f2bf(b.z); u.u[7] = f2bf(b.w);
            *reinterpret_cast<uint4*>(wsl + r * LDP + c) = u.v;
        }
    }
    __syncthreads();

    const int w = t >> 6, l = t & 63;
    const int lr = l & 15;
    const int lk = (l >> 4) * 8;

    f32x4 acc[8];
    #pragma unroll
    for (int cf = 0; cf < 8; ++cf) acc[cf] = f32x4{0.f, 0.f, 0.f, 0.f};

    #pragma unroll
    for (int ks = 0; ks < 4; ++ks) {
        bf16x8 a = *reinterpret_cast<const bf16x8*>(xs + (w * 16 + lr) * LDP + ks * 32 + lk);
        #pragma unroll
        for (int cf = 0; cf < 8; ++cf) {
            bf16x8 b = *reinterpret_cast<const bf16x8*>(wsl + (cf * 16 + lr) * LDP + ks * 32 + lk);
            acc[cf] = __builtin_amdgcn_mfma_f32_16x16x32_bf16(a, b, acc[cf], 0, 0, 0);
        }
    }

    __syncthreads();  // MFMA reads of xs done; reuse xs as store-staging

    // C/D layout: col=lane&15, row=(lane>>4)*4+reg
    #pragma unroll
    for (int cf = 0; cf < 8; ++cf) {
        int col = cf * 16 + lr;
        float bv = (MODE == 1) ? bias[jt * 128 + col] : 0.f;
        #pragma unroll
        for (int reg = 0; reg < 4; ++reg) {
            int rl = w * 16 + (l >> 4) * 4 + reg;
            xs[rl * LDP + col] = f2bf(acc[cf][reg] + bv);
        }
    }
    __syncthreads();

    // coalesced 16B stores from LDS
    #pragma unroll
    for (int i = 0; i < 4; ++i) {
        int e = t + i * 256, r = e >> 4, c = (e & 15) * 8;
        uint4 v = *reinterpret_cast<const uint4*>(xs + r * LDP + c);
        if (MODE == 0)
            *reinterpret_cast<uint4*>(outB + (size_t)(row0 + r) * 128 + c) = v;
        else
            *reinterpret_cast<uint4*>(outB + (size_t)(row0 + r) * 512 + jt * 128 + c) = v;
    }
}

// ---------------------------------------------------------------------------
// K2: PS partials of S0[b,d]=sum_n x1*c, S1[b,d]=sum_n x1*s
// 512 blocks = (b, c64); thread: rr=t>>5 (8 rows/iter), d0=(t&31)*4
// ---------------------------------------------------------------------------
__global__ __launch_bounds__(256) void k_reduceS(
    const ushort* __restrict__ x1b, const float* __restrict__ pos,
    float* __restrict__ PS)
{
    int b = blockIdx.x >> 6, c64 = blockIdx.x & 63;
    int rr = threadIdx.x >> 5, d0 = (threadIdx.x & 31) * 4;
    float a0[4] = {0,0,0,0}, a1[4] = {0,0,0,0};
    #pragma unroll
    for (int i = 0; i < 8; ++i) {
        int n = c64 * 64 + i * 8 + rr;
        size_t r = (size_t)b * Nn + n;
        ushort4 xv = *reinterpret_cast<const ushort4*>(x1b + r * 128 + d0);
        float4 p = *reinterpret_cast<const float4*>(pos + (size_t)n * 128 + d0);
        float x0 = bf2f(xv.x), x1 = bf2f(xv.y), x2 = bf2f(xv.z), x3 = bf2f(xv.w);
        a0[0] += x0 * p.y; a1[0] += x0 * p.x;
        a0[1] += x1 * p.y; a1[1] += x1 * p.x;
        a0[2] += x2 * p.w; a1[2] += x2 * p.z;
        a0[3] += x3 * p.w; a1[3] += x3 * p.z;
    }
    __shared__ float redA[8][128], redB[8][128];
    #pragma unroll
    for (int j = 0; j < 4; ++j) { redA[rr][d0 + j] = a0[j]; redB[rr][d0 + j] = a1[j]; }
    __syncthreads();
    int tt = threadIdx.x;
    float s = 0.f;
    if (tt < 128) {
        #pragma unroll
        for (int k = 0; k < 8; ++k) s += redA[k][tt];
    } else {
        #pragma unroll
        for (int k = 0; k < 8; ++k) s += redB[k][tt - 128];
    }
    PS[(size_t)blockIdx.x * 256 + tt] = s;
}

__global__ __launch_bounds__(256) void k_finS(
    const float* __restrict__ PS, float* __restrict__ S0, float* __restrict__ S1)
{
    int b = blockIdx.x, t = threadIdx.x;
    float s = 0.f;
    #pragma unroll 8
    for (int c = 0; c < 64; ++c) s += PS[(size_t)(b * 64 + c) * 256 + t];
    if (t < 128) S0[b * 128 + t] = s;
    else         S1[b * 128 + (t - 128)] = s;
}

// ---------------------------------------------------------------------------
// K4: PT partials of T[b,h,d] = sum_n rfe; same block/thread layout as K2
// ---------------------------------------------------------------------------
__global__ __launch_bounds__(256) void k_reduceT(
    const ushort* __restrict__ x1b, const ushort* __restrict__ phi,
    const float* __restrict__ pos, const float* __restrict__ S0,
    const float* __restrict__ S1, float* __restrict__ PT)
{
    int b = blockIdx.x >> 6, c64 = blockIdx.x & 63;
    int rr = threadIdx.x >> 5, d0 = (threadIdx.x & 31) * 4;
    float4 S0v = *reinterpret_cast<const float4*>(S0 + b * 128 + d0);
    float4 S1v = *reinterpret_cast<const float4*>(S1 + b * 128 + d0);
    float acc[4][4];
    #pragma unroll
    for (int h = 0; h < 4; ++h)
        #pragma unroll
        for (int j = 0; j < 4; ++j) acc[h][j] = 0.f;

    #pragma unroll 2
    for (int i = 0; i < 8; ++i) {
        int n = c64 * 64 + i * 8 + rr;
        size_t r = (size_t)b * Nn + n;
        ushort4 xv4 = *reinterpret_cast<const ushort4*>(x1b + r * 128 + d0);
        float4 p = *reinterpret_cast<const float4*>(pos + (size_t)n * 128 + d0);
        float xv[4] = {bf2f(xv4.x), bf2f(xv4.y), bf2f(xv4.z), bf2f(xv4.w)};
        float cc[4] = {p.y, p.y, p.w, p.w};
        float ss[4] = {p.x, p.x, p.z, p.z};
        float fec[4], fn[4];
        #pragma unroll
        for (int j = 0; j < 4; ++j) {
            float f0 = ((j < 2) ? ((j == 0) ? S0v.x : S0v.y) : ((j == 2) ? S0v.z : S0v.w)) - xv[j] * cc[j];
            float f1 = xv[j] * ss[j] - ((j < 2) ? ((j == 0) ? S1v.x : S1v.y) : ((j == 2) ? S1v.z : S1v.w));
            fn[j] = sqrtf(f0 * f0 + f1 * f1);
            fec[j] = f0 * cc[j] - f1 * ss[j];
        }
        #pragma unroll
        for (int h = 0; h < 4; ++h) {
            ushort4 ph4 = *reinterpret_cast<const ushort4*>(phi + r * 512 + h * 128 + d0);
            float ph[4] = {bf2f(ph4.x), bf2f(ph4.y), bf2f(ph4.z), bf2f(ph4.w)};
            #pragma unroll
            for (int j = 0; j < 4; ++j)
                acc[h][j] += fmaxf(0.f, fminf(1.f, fn[j] - ph[j])) * fec[j];
        }
    }
    __shared__ float red[8][512];
    #pragma unroll
    for (int h = 0; h < 4; ++h)
        #pragma unroll
        for (int j = 0; j < 4; ++j) red[rr][h * 128 + d0 + j] = acc[h][j];
    __syncthreads();
    int tt = threadIdx.x;
    #pragma unroll
    for (int q = 0; q < 2; ++q) {
        int idx = tt + q * 256;
        float s = 0.f;
        #pragma unroll
        for (int k = 0; k < 8; ++k) s += red[k][idx];
        PT[(size_t)blockIdx.x * 512 + idx] = s;
    }
}

__global__ __launch_bounds__(256) void k_finT(
    const float* __restrict__ PT, float* __restrict__ T)
{
    int idx = blockIdx.x * 256 + threadIdx.x;   // 0..4095
    int b = idx >> 9, lo = idx & 511;
    float s = 0.f;
    #pragma unroll 8
    for (int c = 0; c < 64; ++c) s += PT[(size_t)b * 32768 + c * 512 + lo];
    T[idx] = s;
}

// ---------------------------------------------------------------------------
// K5: wave per row: inv -> comb MLP -> m = x1+comb -> LayerNorm -> mnB (bf16)
// lane l covers d = 2l, 2l+1
// ---------------------------------------------------------------------------
__global__ __launch_bounds__(256) void k_comb_ln(
    const ushort* __restrict__ x1b, const ushort* __restrict__ phi,
    const float* __restrict__ pos, const float* __restrict__ S0,
    const float* __restrict__ S1, const float* __restrict__ T,
    const float* __restrict__ Wc1, const float* __restrict__ bc1,
    const float* __restrict__ Wc2, const float* __restrict__ bc2,
    const float* __restrict__ lng, const float* __restrict__ lnb,
    ushort* __restrict__ mnB)
{
    int w = threadIdx.x >> 6, l = threadIdx.x & 63;
    int rrow = blockIdx.x * 4 + w;
    int b = rrow >> 12;
    int n = rrow & 4095;
    int d0 = 2 * l;
    size_t r = (size_t)rrow;

    ushort2 xv2 = *reinterpret_cast<const ushort2*>(x1b + r * 128 + d0);
    float2 p2 = *reinterpret_cast<const float2*>(pos + (size_t)n * 128 + d0);
    float2 s0 = *reinterpret_cast<const float2*>(S0 + b * 128 + d0);
    float2 s1 = *reinterpret_cast<const float2*>(S1 + b * 128 + d0);
    float cc = p2.y, ss = p2.x;   // same pair for both d0, d0+1

    float m[2];
    float xv[2] = {bf2f(xv2.x), bf2f(xv2.y)};
    float S0a[2] = {s0.x, s0.y}, S1a[2] = {s1.x, s1.y};
    #pragma unroll
    for (int q = 0; q < 2; ++q) {
        float f0 = S0a[q] - xv[q] * cc;
        float f1 = xv[q] * ss - S1a[q];
        float fn = sqrtf(f0 * f0 + f1 * f1);
        float fec = f0 * cc - f1 * ss;
        float inv[4];
        #pragma unroll
        for (int h = 0; h < 4; ++h) {
            float ph = bf2f(phi[r * 512 + h * 128 + d0 + q]);
            float res = fmaxf(0.f, fminf(1.f, fn - ph));
            inv[h] = (T[(b * 4 + h) * 128 + d0 + q] - res * fec) * (1.f / (float)Nn);
        }
        float comb = bc2[0];
        #pragma unroll
        for (int h = 0; h < 4; ++h) {
            float u = bc1[h];
            #pragma unroll
            for (int h2 = 0; h2 < 4; ++h2) u += Wc1[h * 4 + h2] * inv[h2];
            comb += fmaxf(u, 0.f) * Wc2[h];
        }
        m[q] = xv[q] + comb;
    }

    float s = m[0] + m[1];
    #pragma unroll
    for (int off = 32; off; off >>= 1) s += __shfl_xor(s, off);
    float mu = s * (1.f / 128.f);
    float e0 = m[0] - mu, e1 = m[1] - mu;
    float v = e0 * e0 + e1 * e1;
    #pragma unroll
    for (int off = 32; off; off >>= 1) v += __shfl_xor(v, off);
    float rstd = rsqrtf(v * (1.f / 128.f) + 1e-6f);
    ushort2 o;
    o.x = f2bf(e0 * rstd * lng[d0] + lnb[d0]);
    o.y = f2bf(e1 * rstd * lng[d0 + 1] + lnb[d0 + 1]);
    *reinterpret_cast<ushort2*>(mnB + r * 128 + d0) = o;
}

// ---------------------------------------------------------------------------
// K6: fused FFN: out = relu(mn @ Wf1^T + b1) @ Wf2^T + b2
// ---------------------------------------------------------------------------
__global__ __launch_bounds__(256) void k_ffn(
    const ushort* __restrict__ mnB, const float* __restrict__ Wf1,
    const float* __restrict__ bf1, const float* __restrict__ Wf2,
    const float* __restrict__ bf2, float* __restrict__ out)
{
    __shared__ __align__(16) ushort xs[64 * LDP];
    __shared__ __align__(16) ushort wsl[128 * LDP];
    const int t = threadIdx.x;
    const int row0 = blockIdx.x * 64;

    #pragma unroll
    for (int i = 0; i < 4; ++i) {
        int e = t + i * 256, r = e >> 4, c = (e & 15) * 8;
        uint4 v = *reinterpret_cast<const uint4*>(mnB + (size_t)(row0 + r) * 128 + c);
        *reinterpret_cast<uint4*>(xs + r * LDP + c) = v;
    }
    #pragma unroll
    for (int i = 0; i < 8; ++i) {
        int e = t + i * 256, r = e >> 4, c = (e & 15) * 8;
        const float* p = Wf1 + (size_t)r * 128 + c;
        float4 a = *reinterpret_cast<const float4*>(p);
        float4 b = *reinterpret_cast<const float4*>(p + 4);
        U8 u;
        u.u[0] = f2bf(a.x); u.u[1] = f2bf(a.y); u.u[2] = f2bf(a.z); u.u[3] = f2bf(a.w);
        u.u[4] = f2bf(b.x); u.u[5] = f2bf(b.y); u.u[6] = f2bf(b.z); u.u[7] = f2bf(b.w);
        *reinterpret_cast<uint4*>(wsl + r * LDP + c) = u.v;
    }
    __syncthreads();

    const int w = t >> 6, l = t & 63;
    const int lr = l & 15;
    const int lk = (l >> 4) * 8;

    f32x4 acc[8];
    #pragma unroll
    for (int cf = 0; cf < 8; ++cf) acc[cf] = f32x4{0.f, 0.f, 0.f, 0.f};
    #pragma unroll
    for (int ks = 0; ks < 4; ++ks) {
        bf16x8 a = *reinterpret_cast<const bf16x8*>(xs + (w * 16 + lr) * LDP + ks * 32 + lk);
        #pragma unroll
        for (int cf = 0; cf < 8; ++cf) {
            bf16x8 b = *reinterpret_cast<const bf16x8*>(wsl + (cf * 16 + lr) * LDP + ks * 32 + lk);
            acc[cf] = __builtin_amdgcn_mfma_f32_16x16x32_bf16(a, b, acc[cf], 0, 0, 0);
        }
    }

    __syncthreads();  // all MFMA reads of xs/wsl done

    // h1 = relu(acc + b1) -> back into xs (bf16)
    #pragma unroll
    for (int cf = 0; cf < 8; ++cf) {
        int col = cf * 16 + lr;
        float bv = bf1[col];
        #pragma unroll
        for (int reg = 0; reg < 4; ++reg) {
            int rl = w * 16 + (l >> 4) * 4 + reg;
            xs[rl * LDP + col] = f2bf(fmaxf(acc[cf][reg] + bv, 0.f));
        }
    }
    // restage wsl with Wf2
    #pragma unroll
    for (int i = 0; i < 8; ++i) {
        int e = t + i * 256, r = e >> 4, c = (e & 15) * 8;
        const float* p = Wf2 + (size_t)r * 128 + c;
        float4 a = *reinterpret_cast<const float4*>(p);
        float4 b = *reinterpret_cast<const float4*>(p + 4);
        U8 u;
        u.u[0] = f2bf(a.x); u.u[1] = f2bf(a.y); u.u[2] = f2bf(a.z); u.u[3] = f2bf(a.w);
        u.u[4] = f2bf(b.x); u.u[5] = f2bf(b.y); u.u[6] = f2bf(b.z); u.u[7] = f2bf(b.w);
        *reinterpret_cast<uint4*>(wsl + r * LDP + c) = u.v;
    }
    __syncthreads();

    #pragma unroll
    for (int cf = 0; cf < 8; ++cf) acc[cf] = f32x4{0.f, 0.f, 0.f, 0.f};
    #pragma unroll
    for (int ks = 0; ks < 4; ++ks) {
        bf16x8 a = *reinterpret_cast<const bf16x8*>(xs + (w * 16 + lr) * LDP + ks * 32 + lk);
        #pragma unroll
        for (int cf = 0; cf < 8; ++cf) {
            bf16x8 b = *reinterpret_cast<const bf16x8*>(wsl + (cf * 16 + lr) * LDP + ks * 32 + lk);
            acc[cf] = __builtin_amdgcn_mfma_f32_16x16x32_bf16(a, b, acc[cf], 0, 0, 0);
        }
    }

    #pragma unroll
    for (int cf = 0; cf < 8; ++cf) {
        int col = cf * 16 + lr;
        float bv = bf2[col];
        #pragma unroll
        for (int reg = 0; reg < 4; ++reg) {
            int r = row0 + w * 16 + (l >> 4) * 4 + reg;
            out[(size_t)r * 128 + col] = acc[cf][reg] + bv;
        }
    }
}

// ---------------------------------------------------------------------------
extern "C" void kernel_launch(void* const* d_in, const int* in_sizes, int n_in,
                              void* d_out, int out_size, void* d_ws, size_t ws_size,
                              hipStream_t stream)
{
    const float* x    = (const float*)d_in[0];
    const float* pos  = (const float*)d_in[1];
    const float* Wlt  = (const float*)d_in[2];
    const float* Wphi = (const float*)d_in[3];
    const float* bphi = (const float*)d_in[4];
    const float* Wc1  = (const float*)d_in[5];
    const float* bc1  = (const float*)d_in[6];
    const float* Wc2  = (const float*)d_in[7];
    const float* bc2  = (const float*)d_in[8];
    const float* lng  = (const float*)d_in[9];
    const float* lnb  = (const float*)d_in[10];
    const float* Wf1  = (const float*)d_in[11];
    const float* bf1  = (const float*)d_in[12];
    const float* Wf2  = (const float*)d_in[13];
    const float* bf2  = (const float*)d_in[14];

    float* ws = (float*)d_ws;
    ushort* x1b = (ushort*)ws;                 // [BN*128] bf16   8 MB
    ushort* mnB = (ushort*)(ws + 2097152);     // [BN*128] bf16   8 MB
    float* S0   = ws + 4194304;                // [1024]
    float* S1   = S0 + 1024;                   // [1024]
    float* T    = S1 + 1024;                   // [4096]
    float* PS   = T + 4096;                    // [512*256]       512 KB
    float* PT   = PS + 131072;                 // [512*512]       1 MB
    ushort* phi = (ushort*)(ws + 4593664);     // [BN*512] bf16   32 MB
    float* out  = (float*)d_out;

    k_mfma_gemm<0><<<dim3(BN / 64), 256, 0, stream>>>(x, Wlt, nullptr, pos, x1b);
    k_reduceS<<<dim3(512), 256, 0, stream>>>(x1b, pos, PS);
    k_finS<<<dim3(Bb), 256, 0, stream>>>(PS, S0, S1);
    k_mfma_gemm<1><<<dim3(BN / 64, 4), 256, 0, stream>>>(x1b, Wphi, bphi, pos, phi);
    k_reduceT<<<dim3(512), 256, 0, stream>>>(x1b, phi, pos, S0, S1, PT);
    k_finT<<<dim3(16), 256, 0, stream>>>(PT, T);
    k_comb_ln<<<dim3(BN / 4), 256, 0, stream>>>(x1b, phi, pos, S0, S1, T,
                                                Wc1, bc1, Wc2, bc2, lng, lnb, mnB);
    k_ffn<<<dim3(BN / 64), 256, 0, stream>>>(mnB, Wf1, bf1, Wf2, bf2, out);
}